// Round 5
// baseline (609.482 us; speedup 1.0000x reference)
//
#include <hip/hip_runtime.h>

typedef __attribute__((ext_vector_type(8))) short short8;
typedef __attribute__((ext_vector_type(4))) float floatx4;

static __device__ __forceinline__ unsigned short f2bf(float x) {
    unsigned int u = __float_as_uint(x);
    u += 0x7fffu + ((u >> 16) & 1u);
    return (unsigned short)(u >> 16);
}
static __device__ __forceinline__ float bf2f(unsigned short h) {
    return __uint_as_float(((unsigned int)h) << 16);
}

// ---------------- K1: histogram of iid ----------------
__global__ void k_hist(const int* __restrict__ iid, int* __restrict__ counts, int N) {
    int n = blockIdx.x * blockDim.x + threadIdx.x;
    if (n < N) atomicAdd(&counts[iid[n]], 1);
}

// ---------------- K2: fp32->bf16 convert + count-weighted stats (one feat pass) ------
__global__ __launch_bounds__(256) void k_cvtstats(const float* __restrict__ feat,
                                                  const int* __restrict__ counts,
                                                  unsigned short* __restrict__ featb,
                                                  float* __restrict__ dsum, float* __restrict__ dsumsq,
                                                  int V) {
    int tid = threadIdx.x;
    int r2 = tid >> 7, d = tid & 127;
    float s = 0.f, qa = 0.f;
    for (int vp = blockIdx.x; vp * 2 < V; vp += gridDim.x) {
        int v = vp * 2 + r2;
        if (v >= V) continue;
        float f = feat[(size_t)v * 128 + d];
        featb[(size_t)v * 128 + d] = f2bf(f);
        float c = (float)counts[v];
        if (c != 0.f) { s += c * f; qa += c * f * f; }
    }
    __shared__ float red[256];
    red[tid] = s; __syncthreads();
    if (tid < 128) atomicAdd(&dsum[d], red[tid] + red[tid + 128]);
    __syncthreads();
    red[tid] = qa; __syncthreads();
    if (tid < 128) atomicAdd(&dsumsq[d], red[tid] + red[tid + 128]);
}

// ---------------- K3: merged prep (block 0: wut+cvec) + fv (blocks 1..) --------------
// Every block recomputes scale/shift inline from dsum/dsumsq (no cross-block deps).
// wut[h][d] = bf16(scale[d]*Wu[d][h]); cvec[h] = sum_d shift[d]*Wu[d][h]
// fv[b][h]  = xhat_last@Wv + bv  where xhat = scale*x+shift
__global__ __launch_bounds__(256) void k_mid(const float* __restrict__ feat, const int* __restrict__ iid,
                                             const int* __restrict__ last,
                                             const float* __restrict__ dsum, const float* __restrict__ dsumsq,
                                             const float* __restrict__ gamma, const float* __restrict__ beta,
                                             const float* __restrict__ Wu, const float* __restrict__ Wv,
                                             const float* __restrict__ bv,
                                             unsigned short* __restrict__ wut, float* __restrict__ cvec,
                                             float* __restrict__ fv, float invN, int B) {
    __shared__ float sScale[128], sShift[128];
    __shared__ float sx[32][128];
    int tid = threadIdx.x;
    if (tid < 128) {
        float mean = dsum[tid] * invN;
        float var  = dsumsq[tid] * invN - mean * mean;
        float sc   = gamma[tid] * rsqrtf(var + 1e-5f);
        sScale[tid] = sc;
        sShift[tid] = beta[tid] - mean * sc;
    }
    __syncthreads();
    if (blockIdx.x == 0) {
        for (int i = tid; i < 16384; i += 256) {
            int d2 = i >> 7, h = i & 127;
            wut[h * 128 + d2] = f2bf(sScale[d2] * Wu[i]);   // Wu[i]=Wu[d2*128+h], coalesced read
        }
        if (tid < 128) {
            float a = 0.f;
            for (int d2 = 0; d2 < 128; ++d2) a += sShift[d2] * Wu[d2 * 128 + tid];
            cvec[tid] = a;
        }
        return;
    }
    int b0 = (blockIdx.x - 1) * 32;
    int h = tid & 127, half = tid >> 7;
    for (int g = half; g < 32; g += 2) {
        int b = b0 + g;
        int row = (b < B) ? iid[last[b]] : 0;
        sx[g][h] = feat[(size_t)row * 128 + h] * sScale[h] + sShift[h];
    }
    __syncthreads();
    float acc[16];
#pragma unroll
    for (int g = 0; g < 16; ++g) acc[g] = 0.f;
    for (int d2 = 0; d2 < 128; ++d2) {
        float w = Wv[d2 * 128 + h];          // coalesced, broadcast across halves
#pragma unroll
        for (int g = 0; g < 16; ++g) acc[g] += sx[half * 16 + g][d2] * w;
    }
    float cb = bv[h];
    for (int g = 0; g < 16; ++g) {
        int b = b0 + half * 16 + g;
        if (b < B) fv[(size_t)b * 128 + h] = acc[g] + cb;
    }
}

// ---------------- K4: fused main — ONE barrier per 64-node tile ----------------
// iter: B | stage(T+1,DMA) | fv-prefetch(T) | loadRegs(T+2) | scanPhase(T-1: ex, denom,
//       S@A via MFMA, rstu atomics) | MFMA(T) | epilogue(T)->sEp
__global__ __launch_bounds__(256, 3) void k_main(
        const unsigned short* __restrict__ featb, const int* __restrict__ iid,
        const int* __restrict__ seg, const unsigned short* __restrict__ wut,
        const float* __restrict__ fv, const float* __restrict__ we_g,
        const float* __restrict__ cvec,
        float* __restrict__ denom, float* __restrict__ rstu,
        int N, int numTiles) {
    __shared__ unsigned short sA[3][64 * 128];   // 48 KB, XOR-swizzled 16B chunks
    __shared__ int   sSeg[3][64];
    __shared__ float sEp[2][4][64];

    int tid = threadIdx.x;
    int wv = tid >> 6, lane = tid & 63, q = lane >> 4, c = lane & 15;
    int p2 = lane & 15;
    int rowbase = wv * 16 + (lane >> 4);
    int h0 = wv * 32 + c;

    // one-time: B fragments + per-wave constants
    short8 bfr[2][4];
    float we2[2], cv[2];
#pragma unroll
    for (int t = 0; t < 2; ++t) {
        int h = (2 * wv + t) * 16 + c;
        we2[t] = we_g[h];
        cv[t]  = cvec[h];
#pragma unroll
        for (int kc = 0; kc < 4; ++kc)
            bfr[t][kc] = *(const short8*)(wut + h * 128 + kc * 32 + q * 8);
    }

    int G = gridDim.x;
    if (blockIdx.x >= numTiles) return;

    int iidR[4]; int segR;
    auto loadRegs = [&](int T2) {
        int n0 = T2 << 6;
#pragma unroll
        for (int k = 0; k < 4; ++k)
            iidR[k] = iid[min(n0 + rowbase + 4 * k, N - 1)];
        segR = seg[min(n0 + lane, N - 1)];
    };
    auto stage = [&](int buf) {
        unsigned short* sAb = &sA[buf][0];
#pragma unroll
        for (int k = 0; k < 4; ++k) {
            int row = rowbase + 4 * k;
            int j = (p2 & 8) | ((p2 & 7) ^ (row & 7));
            const unsigned short* g = featb + (size_t)iidR[k] * 128 + j * 8;
            __builtin_amdgcn_global_load_lds(
                (const __attribute__((address_space(1))) void*)g,
                (__attribute__((address_space(3))) void*)(sAb + wv * 2048 + k * 512),
                16, 0, 0);
        }
        if (tid < 64) sSeg[buf][tid] = segR;
    };

    // scanPhase(T-1): every wave redundantly computes ex[node=lane]; wave0 does denom;
    // S (16 x 64, bf16 ex) built via shuffles; rst_part = S @ A_tile via 4 MFMAs/wave.
    auto scanPhase = [&](int bufP, int Tp, int epb) {
        float s = sEp[epb][0][lane] + sEp[epb][1][lane]
                + sEp[epb][2][lane] + sEp[epb][3][lane];
        int n = (Tp << 6) + lane;
        int sgl = sSeg[bufP][lane];
        float ex = (n < N) ? __expf(s) : 0.f;
        if (wv == 0) {  // segmented suffix-sum over sorted lanes -> 1 atomic per segment
            float v = ex;
#pragma unroll
            for (int off = 1; off < 64; off <<= 1) {
                float o = __shfl_down(v, off);
                int  so = __shfl_down(sgl, off);
                if (lane + off < 64 && so == sgl) v += o;
            }
            bool head = (lane == 0) || (sSeg[bufP][lane - 1] != sgl);
            if (head && v != 0.f) atomicAdd(&denom[sgl], v);
        }
        int s0 = sSeg[bufP][0];
        int range = sSeg[bufP][63] - s0;
        unsigned short exb = f2bf(ex);
        int packed = ((sgl - s0) << 16) | (int)exb;
        if (range < 16) {
            // A-op frags of S: row m=c (seg_local), k=node
            short8 sfrag[2];
#pragma unroll
            for (int kc = 0; kc < 2; ++kc)
#pragma unroll
                for (int j = 0; j < 8; ++j) {
                    int t2 = __shfl(packed, kc * 32 + q * 8 + j);
                    sfrag[kc][j] = ((t2 >> 16) == c) ? (short)(t2 & 0xffff) : (short)0;
                }
#pragma unroll
            for (int t = 0; t < 2; ++t) {
                int d = (2 * wv + t) * 16 + c;
                int cch = d >> 3, w7 = d & 7, c8 = cch & 7, hi8 = cch & 8;
                floatx4 racc = (floatx4)(0.f);
#pragma unroll
                for (int kc = 0; kc < 2; ++kc) {
                    short8 bfrag;
#pragma unroll
                    for (int j = 0; j < 8; ++j) {
                        int node = kc * 32 + q * 8 + j;
                        int jx = hi8 | (c8 ^ (node & 7));
                        bfrag[j] = (short)sA[bufP][node * 128 + jx * 8 + w7];
                    }
                    racc = __builtin_amdgcn_mfma_f32_16x16x32_bf16(sfrag[kc], bfrag, racc, 0, 0, 0);
                }
#pragma unroll
                for (int r = 0; r < 4; ++r) {
                    int sl = q * 4 + r;   // C layout: row=q*4+r (seg_local), col=c (in d)
                    if (sl <= range && racc[r] != 0.f)
                        atomicAdd(&rstu[((size_t)(s0 + sl) << 7) + d], racc[r]);
                }
            }
        } else {
            // rare fallback: VALU segmented scan (fp32 ex via shuffles)
            int sd = tid & 127, grp = tid >> 7;
            int cch = sd >> 3, w7 = sd & 7, c8 = cch & 7, hi8 = cch & 8;
            float a = 0.f;
            int j0 = grp * 32;
            int cur = sSeg[bufP][j0];
            for (int j = j0; j < j0 + 32; ++j) {
                int s2 = sSeg[bufP][j];
                float exj = __shfl(ex, j);
                if (s2 != cur) { atomicAdd(&rstu[((size_t)cur << 7) + sd], a); a = 0.f; cur = s2; }
                int jx = hi8 | (c8 ^ (j & 7));
                a += exj * bf2f(sA[bufP][j * 128 + jx * 8 + w7]);
            }
            atomicAdd(&rstu[((size_t)cur << 7) + sd], a);
        }
    };

    int T = blockIdx.x;
    loadRegs(T);
    stage(0);
    if (T + G < numTiles) loadRegs(T + G);
    int it = 0;

    while (true) {
        __syncthreads();   // single barrier: drains stage/loadRegs/atomics all >=3/4 iter old
        int bufC = it % 3;
        bool hn = (T + G < numTiles);
        if (hn) stage((it + 1) % 3);              // DMA earliest (uses regs from prev iter)
        // batched epilogue prefetch for tile T (independent loads, consumed ~800cyc later)
        float fv0[16], fv1[16];
#pragma unroll
        for (int i = 0; i < 16; ++i) {
            int mt = i >> 2, r = i & 3;
            int sg2 = sSeg[bufC][mt * 16 + q * 4 + r];
            const float* fp = fv + ((size_t)sg2 << 7);
            fv0[i] = fp[h0];
            fv1[i] = fp[h0 + 16];
        }
        if (T + 2 * G < numTiles) loadRegs(T + 2 * G);
        if (it > 0) scanPhase((it + 2) % 3, T - G, (it + 1) & 1);

        // ---- main MFMA tile T ----
        floatx4 acc[4][2];
#pragma unroll
        for (int mt = 0; mt < 4; ++mt)
#pragma unroll
            for (int t = 0; t < 2; ++t) acc[mt][t] = (floatx4)(0.f);
#pragma unroll
        for (int kc = 0; kc < 4; ++kc) {
            int jj = 4 * kc + q;
            int pofs = ((jj & 8) | ((jj & 7) ^ (c & 7))) * 8;
            short8 a0 = *(const short8*)&sA[bufC][( 0 + c) * 128 + pofs];
            short8 a1 = *(const short8*)&sA[bufC][(16 + c) * 128 + pofs];
            short8 a2 = *(const short8*)&sA[bufC][(32 + c) * 128 + pofs];
            short8 a3 = *(const short8*)&sA[bufC][(48 + c) * 128 + pofs];
#pragma unroll
            for (int t = 0; t < 2; ++t) {
                acc[0][t] = __builtin_amdgcn_mfma_f32_16x16x32_bf16(a0, bfr[t][kc], acc[0][t], 0, 0, 0);
                acc[1][t] = __builtin_amdgcn_mfma_f32_16x16x32_bf16(a1, bfr[t][kc], acc[1][t], 0, 0, 0);
                acc[2][t] = __builtin_amdgcn_mfma_f32_16x16x32_bf16(a2, bfr[t][kc], acc[2][t], 0, 0, 0);
                acc[3][t] = __builtin_amdgcn_mfma_f32_16x16x32_bf16(a3, bfr[t][kc], acc[3][t], 0, 0, 0);
            }
        }
        // ---- epilogue: e partials (prefetched fv) ----
#pragma unroll
        for (int i = 0; i < 16; ++i) {
            int mt = i >> 2, r = i & 3;
            int nl = mt * 16 + q * 4 + r;
            float u0 = acc[mt][0][r] + fv0[i] + cv[0];
            float u1 = acc[mt][1][r] + fv1[i] + cv[1];
            float p = we2[0] * __builtin_amdgcn_rcpf(1.f + __expf(-u0))
                    + we2[1] * __builtin_amdgcn_rcpf(1.f + __expf(-u1));
            p += __shfl_xor(p, 1);
            p += __shfl_xor(p, 2);
            p += __shfl_xor(p, 4);
            p += __shfl_xor(p, 8);
            if (c == 0) sEp[it & 1][wv][nl] = p;
        }
        if (!hn) break;
        T += G; ++it;
    }
    __syncthreads();
    scanPhase(it % 3, T, it & 1);
}

// ---------------- K5: out = (scale*rstu/denom + shift*(denom>0)) @ W_out ----------------
__global__ __launch_bounds__(256) void k_out(const float* __restrict__ rstu, const float* __restrict__ denomA,
                                             const float* __restrict__ dsum, const float* __restrict__ dsumsq,
                                             const float* __restrict__ gamma, const float* __restrict__ beta,
                                             const float* __restrict__ Wout, float* __restrict__ out,
                                             float invN, int B) {
    __shared__ float sT[128][36];
    __shared__ float sScale[128], sShift[128];
    int t = threadIdx.x;
    if (t < 128) {
        float mean = dsum[t] * invN;
        float var  = dsumsq[t] * invN - mean * mean;
        float sc   = gamma[t] * rsqrtf(var + 1e-5f);
        sScale[t] = sc;
        sShift[t] = beta[t] - mean * sc;
    }
    __syncthreads();
    int b0 = blockIdx.x * 32;
    for (int i = 0; i < 16; ++i) {
        int idx = i * 256 + t;
        int r = idx >> 7, d = idx & 127;
        int b = min(b0 + r, B - 1);
        float dn = denomA[b];
        float inv = (dn > 0.f) ? 1.f / dn : 0.f;
        float msk = (dn > 0.f) ? 1.f : 0.f;
        sT[d][r] = rstu[((size_t)b << 7) + d] * sScale[d] * inv + sShift[d] * msk;
    }
    __syncthreads();
    float acc[32];
#pragma unroll
    for (int r = 0; r < 32; ++r) acc[r] = 0.f;
    for (int dd = 0; dd < 128; ++dd) {
        float w = Wout[dd * 256 + t];
        const float4* row = (const float4*)&sT[dd][0];
#pragma unroll
        for (int r4 = 0; r4 < 8; ++r4) {
            float4 v = row[r4];
            acc[r4 * 4 + 0] += w * v.x;
            acc[r4 * 4 + 1] += w * v.y;
            acc[r4 * 4 + 2] += w * v.z;
            acc[r4 * 4 + 3] += w * v.w;
        }
    }
    for (int r = 0; r < 32; ++r)
        if (b0 + r < B) out[(size_t)(b0 + r) * 256 + t] = acc[r];
}

extern "C" void kernel_launch(void* const* d_in, const int* in_sizes, int n_in,
                              void* d_out, int out_size, void* d_ws, size_t ws_size,
                              hipStream_t stream) {
    const float* feat  = (const float*)d_in[0];
    const int*   iid   = (const int*)d_in[1];
    const int*   seg   = (const int*)d_in[2];
    const int*   last  = (const int*)d_in[3];
    const float* gamma = (const float*)d_in[4];
    const float* beta  = (const float*)d_in[5];
    const float* Wu    = (const float*)d_in[6];
    const float* Wv    = (const float*)d_in[7];
    const float* bv    = (const float*)d_in[8];
    const float* we    = (const float*)d_in[9];
    const float* Wout  = (const float*)d_in[10];
    float* out = (float*)d_out;

    int V = in_sizes[0] / 128;
    int N = in_sizes[1];
    int B = in_sizes[3];
    float invN = 1.0f / (float)N;

    char* w = (char*)d_ws;
    size_t off = 0;
    auto alloc = [&](size_t bytes) -> void* {
        void* p = w + off;
        off += (bytes + 255) & ~(size_t)255;
        return p;
    };
    // zero-init region
    int*   counts = (int*)alloc((size_t)V * 4);
    float* dsum   = (float*)alloc(512);
    float* dsumsq = (float*)alloc(512);
    float* denom  = (float*)alloc((size_t)B * 4);
    float* rstu   = (float*)alloc((size_t)B * 128 * 4);
    size_t zero_bytes = off;
    // rest
    unsigned short* wut = (unsigned short*)alloc(128 * 128 * 2);
    float* cvec   = (float*)alloc(512);
    float* fv     = (float*)alloc((size_t)B * 128 * 4);
    unsigned short* featb = (unsigned short*)alloc((size_t)V * 128 * 2);
    (void)ws_size; (void)n_in; (void)out_size;

    hipMemsetAsync(d_ws, 0, zero_bytes, stream);

    k_hist<<<(N + 255) / 256, 256, 0, stream>>>(iid, counts, N);
    k_cvtstats<<<1024, 256, 0, stream>>>(feat, counts, featb, dsum, dsumsq, V);
    k_mid<<<1 + (B + 31) / 32, 256, 0, stream>>>(feat, iid, last, dsum, dsumsq, gamma, beta,
                                                 Wu, Wv, bv, wut, cvec, fv, invN, B);
    int numTiles = (N + 63) / 64;
    k_main<<<768, 256, 0, stream>>>(featb, iid, seg, wut, fv, we, cvec, denom, rstu, N, numTiles);
    k_out<<<(B + 31) / 32, 256, 0, stream>>>(rstu, denom, dsum, dsumsq, gamma, beta, Wout, out, invN, B);
}

// Round 6
// 467.435 us; speedup vs baseline: 1.3039x; 1.3039x over previous
//
#include <hip/hip_runtime.h>

typedef __attribute__((ext_vector_type(8))) short short8;
typedef __attribute__((ext_vector_type(4))) float floatx4;

static __device__ __forceinline__ unsigned short f2bf(float x) {
    unsigned int u = __float_as_uint(x);
    u += 0x7fffu + ((u >> 16) & 1u);
    return (unsigned short)(u >> 16);
}
static __device__ __forceinline__ float bf2f(unsigned short h) {
    return __uint_as_float(((unsigned int)h) << 16);
}

// ---------------- K1: histogram of iid ----------------
__global__ void k_hist(const int* __restrict__ iid, int* __restrict__ counts, int N) {
    int n = blockIdx.x * blockDim.x + threadIdx.x;
    if (n < N) atomicAdd(&counts[iid[n]], 1);
}

// ---------------- K2: fp32->bf16 convert + count-weighted stats (one feat pass) ------
__global__ __launch_bounds__(256) void k_cvtstats(const float* __restrict__ feat,
                                                  const int* __restrict__ counts,
                                                  unsigned short* __restrict__ featb,
                                                  float* __restrict__ dsum, float* __restrict__ dsumsq,
                                                  int V) {
    int tid = threadIdx.x;
    int r2 = tid >> 7, d = tid & 127;
    float s = 0.f, qa = 0.f;
    for (int vp = blockIdx.x; vp * 2 < V; vp += gridDim.x) {
        int v = vp * 2 + r2;
        if (v >= V) continue;
        float f = feat[(size_t)v * 128 + d];
        featb[(size_t)v * 128 + d] = f2bf(f);
        float c = (float)counts[v];
        if (c != 0.f) { s += c * f; qa += c * f * f; }
    }
    __shared__ float red[256];
    red[tid] = s; __syncthreads();
    if (tid < 128) atomicAdd(&dsum[d], red[tid] + red[tid + 128]);
    __syncthreads();
    red[tid] = qa; __syncthreads();
    if (tid < 128) atomicAdd(&dsumsq[d], red[tid] + red[tid + 128]);
}

// ---------------- K3: merged prep (block 0: wut+cvec) + fv (blocks 1..) --------------
// scale/shift recomputed inline per block from dsum/dsumsq (no cross-block deps).
// wut[h][d] = bf16(scale[d]*Wu[d][h]); cvec[h] = sum_d shift[d]*Wu[d][h]
// fv[b][h]  = xhat_last@Wv + bv   (xhat = scale*x+shift)
__global__ __launch_bounds__(256) void k_mid(const float* __restrict__ feat, const int* __restrict__ iid,
                                             const int* __restrict__ last,
                                             const float* __restrict__ dsum, const float* __restrict__ dsumsq,
                                             const float* __restrict__ gamma, const float* __restrict__ beta,
                                             const float* __restrict__ Wu, const float* __restrict__ Wv,
                                             const float* __restrict__ bv,
                                             unsigned short* __restrict__ wut, float* __restrict__ cvec,
                                             float* __restrict__ fv, float invN, int B) {
    __shared__ float sScale[128], sShift[128];
    __shared__ float sx[32][128];
    int tid = threadIdx.x;
    if (tid < 128) {
        float mean = dsum[tid] * invN;
        float var  = dsumsq[tid] * invN - mean * mean;
        float sc   = gamma[tid] * rsqrtf(var + 1e-5f);
        sScale[tid] = sc;
        sShift[tid] = beta[tid] - mean * sc;
    }
    __syncthreads();
    if (blockIdx.x == 0) {
        for (int i = tid; i < 16384; i += 256) {
            int d2 = i >> 7, h = i & 127;
            wut[h * 128 + d2] = f2bf(sScale[d2] * Wu[i]);   // Wu[i]=Wu[d2*128+h], coalesced
        }
        if (tid < 128) {
            float a = 0.f;
            for (int d2 = 0; d2 < 128; ++d2) a += sShift[d2] * Wu[d2 * 128 + tid];
            cvec[tid] = a;
        }
        return;
    }
    int b0 = (blockIdx.x - 1) * 32;
    int h = tid & 127, half = tid >> 7;
    for (int g = half; g < 32; g += 2) {
        int b = b0 + g;
        int row = (b < B) ? iid[last[b]] : 0;
        sx[g][h] = feat[(size_t)row * 128 + h] * sScale[h] + sShift[h];
    }
    __syncthreads();
    float acc[16];
#pragma unroll
    for (int g = 0; g < 16; ++g) acc[g] = 0.f;
    for (int d2 = 0; d2 < 128; ++d2) {
        float w = Wv[d2 * 128 + h];
#pragma unroll
        for (int g = 0; g < 16; ++g) acc[g] += sx[half * 16 + g][d2] * w;
    }
    float cb = bv[h];
    for (int g = 0; g < 16; ++g) {
        int b = b0 + half * 16 + g;
        if (b < B) fv[(size_t)b * 128 + h] = acc[g] + cb;
    }
}

// ---------------- K4: pipelined e-kernel (round-3 version + cvec) ----------------
// ex[n] = exp( w_e . sigmoid(bf16(feat[iid[n]]) @ Wu' + cvec + fv[seg[n]]) )
__global__ __launch_bounds__(256, 3) void k_main(
        const unsigned short* __restrict__ featb, const int* __restrict__ iid,
        const int* __restrict__ seg, const unsigned short* __restrict__ wut,
        const float* __restrict__ fv, const float* __restrict__ we_g,
        const float* __restrict__ cvec,
        float* __restrict__ exo, int N, int B, int numTiles) {
    __shared__ unsigned short sA[2][64 * 128];
    __shared__ int   sSeg[2][64];
    __shared__ float sFv[2][4][128];
    __shared__ float sEp[2][4][64];

    int tid = threadIdx.x;
    int wv = tid >> 6, lane = tid & 63, q = lane >> 4, c = lane & 15;
    int p2 = lane & 15;
    int rowbase = wv * 16 + (lane >> 4);

    short8 bfr[2][4];
    float we2[2], cv[2];
#pragma unroll
    for (int t = 0; t < 2; ++t) {
        int h = (2 * wv + t) * 16 + c;
        we2[t] = we_g[h];
        cv[t]  = cvec[h];
#pragma unroll
        for (int kc = 0; kc < 4; ++kc)
            bfr[t][kc] = *(const short8*)(wut + h * 128 + kc * 32 + q * 8);
    }

    if (blockIdx.x >= numTiles) return;

    int iidR[4]; int segR; float2 fvR;
    auto loadRegs = [&](int T) {
        int n0 = T << 6;
#pragma unroll
        for (int k = 0; k < 4; ++k)
            iidR[k] = iid[min(n0 + rowbase + 4 * k, N - 1)];
        segR = seg[min(n0 + (tid & 63), N - 1)];
        int s0 = seg[min(n0, N - 1)];
        int fvrow = min(s0 + (tid >> 6), B - 1);
        fvR = *(const float2*)(fv + (size_t)fvrow * 128 + ((tid << 1) & 127));
    };
    auto stage = [&](int buf) {
        unsigned short* sAb = &sA[buf][0];
#pragma unroll
        for (int k = 0; k < 4; ++k) {
            int row = rowbase + 4 * k;
            int j = (p2 & 8) | ((p2 & 7) ^ (row & 7));
            const unsigned short* g = featb + (size_t)iidR[k] * 128 + j * 8;
            __builtin_amdgcn_global_load_lds(
                (const __attribute__((address_space(1))) void*)g,
                (__attribute__((address_space(3))) void*)(sAb + wv * 2048 + k * 512),
                16, 0, 0);
        }
        if (tid < 64) sSeg[buf][tid] = segR;
        *(float2*)&sFv[buf][tid >> 6][(tid << 1) & 127] = fvR;
    };

    int T = blockIdx.x;
    loadRegs(T);
    stage(0);
    int prevN0 = -1;
    int cur = 0;

    for (;;) {
        int Tn = T + gridDim.x;
        bool hn = (Tn < numTiles);
        if (hn) loadRegs(Tn);
        __syncthreads();            // buf[cur] loads complete; buf[cur^1] readers done
        if (hn) stage(cur ^ 1);

        floatx4 acc[4][2];
#pragma unroll
        for (int mt = 0; mt < 4; ++mt)
#pragma unroll
            for (int t = 0; t < 2; ++t) acc[mt][t] = (floatx4)(0.f);
#pragma unroll
        for (int kc = 0; kc < 4; ++kc) {
            int jj = 4 * kc + q;
            int pofs = ((jj & 8) | ((jj & 7) ^ (c & 7))) * 8;
            short8 a0 = *(const short8*)&sA[cur][( 0 + c) * 128 + pofs];
            short8 a1 = *(const short8*)&sA[cur][(16 + c) * 128 + pofs];
            short8 a2 = *(const short8*)&sA[cur][(32 + c) * 128 + pofs];
            short8 a3 = *(const short8*)&sA[cur][(48 + c) * 128 + pofs];
#pragma unroll
            for (int t = 0; t < 2; ++t) {
                acc[0][t] = __builtin_amdgcn_mfma_f32_16x16x32_bf16(a0, bfr[t][kc], acc[0][t], 0, 0, 0);
                acc[1][t] = __builtin_amdgcn_mfma_f32_16x16x32_bf16(a1, bfr[t][kc], acc[1][t], 0, 0, 0);
                acc[2][t] = __builtin_amdgcn_mfma_f32_16x16x32_bf16(a2, bfr[t][kc], acc[2][t], 0, 0, 0);
                acc[3][t] = __builtin_amdgcn_mfma_f32_16x16x32_bf16(a3, bfr[t][kc], acc[3][t], 0, 0, 0);
            }
        }
        {
            int s0 = sSeg[cur][0];
            int h0 = wv * 32 + c;
#pragma unroll
            for (int mt = 0; mt < 4; ++mt)
#pragma unroll
                for (int r = 0; r < 4; ++r) {
                    int nl = mt * 16 + q * 4 + r;
                    int sg = sSeg[cur][nl];
                    int off = sg - s0;
                    float f0, f1;
                    if (off < 4) {
                        f0 = sFv[cur][off][h0];
                        f1 = sFv[cur][off][h0 + 16];
                    } else {
                        f0 = fv[((size_t)sg << 7) + h0];
                        f1 = fv[((size_t)sg << 7) + h0 + 16];
                    }
                    float u0 = acc[mt][0][r] + f0 + cv[0];
                    float u1 = acc[mt][1][r] + f1 + cv[1];
                    float p = we2[0] * __builtin_amdgcn_rcpf(1.f + __expf(-u0))
                            + we2[1] * __builtin_amdgcn_rcpf(1.f + __expf(-u1));
                    p += __shfl_xor(p, 1);
                    p += __shfl_xor(p, 2);
                    p += __shfl_xor(p, 4);
                    p += __shfl_xor(p, 8);
                    if (c == 0) sEp[cur][wv][nl] = p;
                }
        }
        if (prevN0 >= 0 && tid < 64) {
            int n = prevN0 + tid;
            if (n < N) {
                float s = sEp[cur ^ 1][0][tid] + sEp[cur ^ 1][1][tid]
                        + sEp[cur ^ 1][2][tid] + sEp[cur ^ 1][3][tid];
                exo[n] = __expf(s);
            }
        }
        prevN0 = T << 6;
        if (!hn) break;
        T = Tn; cur ^= 1;
    }
    __syncthreads();
    if (tid < 64) {
        int n = prevN0 + tid;
        if (n < N) {
            float s = sEp[cur][0][tid] + sEp[cur][1][tid]
                    + sEp[cur][2][tid] + sEp[cur][3][tid];
            exo[n] = __expf(s);
        }
    }
}

// ---------------- K5: weighted segment-sum, sequential tiles, DMA-staged ----------------
// denom[b] += sum ex_n (1 atomic/segment); rstu[b][d] += sum ex_n * row_n[d]
__global__ __launch_bounds__(256, 4) void k_sum(
        const unsigned short* __restrict__ featb, const int* __restrict__ iid,
        const int* __restrict__ seg, const float* __restrict__ exo,
        float* __restrict__ denom, float* __restrict__ rstu,
        int N, int numTiles) {
    __shared__ unsigned short sA[2][64 * 128];
    __shared__ int   sSeg[2][64];
    __shared__ float sEx[2][64];

    int tid = threadIdx.x;
    int wv = tid >> 6, lane = tid & 63;
    int p2 = lane & 15;
    int rowbase = wv * 16 + (lane >> 4);

    if (blockIdx.x >= numTiles) return;

    int iidR[4]; int segR; float exR;
    auto loadRegs = [&](int T) {
        int n0 = T << 6;
#pragma unroll
        for (int k = 0; k < 4; ++k)
            iidR[k] = iid[min(n0 + rowbase + 4 * k, N - 1)];
        int n = n0 + lane;
        segR = seg[min(n, N - 1)];
        exR = (wv == 0 && n < N) ? exo[n] : 0.f;
    };
    auto stage = [&](int buf) {
        unsigned short* sAb = &sA[buf][0];
#pragma unroll
        for (int k = 0; k < 4; ++k) {
            int row = rowbase + 4 * k;
            int j = (p2 & 8) | ((p2 & 7) ^ (row & 7));
            const unsigned short* g = featb + (size_t)iidR[k] * 128 + j * 8;
            __builtin_amdgcn_global_load_lds(
                (const __attribute__((address_space(1))) void*)g,
                (__attribute__((address_space(3))) void*)(sAb + wv * 2048 + k * 512),
                16, 0, 0);
        }
        if (tid < 64) { sSeg[buf][tid] = segR; sEx[buf][tid] = exR; }
    };

    // VALU segmented scan over 32-node half-tiles (proven R4 pattern)
    int sd = tid & 127, grp = tid >> 7;
    int cch = sd >> 3;
    int sbase = (cch & 8) * 8 + (sd & 7);
    int c7 = cch & 7;

    int T = blockIdx.x;
    loadRegs(T);
    stage(0);
    int cur = 0;

    for (;;) {
        int Tn = T + gridDim.x;
        bool hn = (Tn < numTiles);
        if (hn) loadRegs(Tn);
        __syncthreads();            // buf[cur] complete; buf[cur^1] readers done
        if (hn) stage(cur ^ 1);

        // denominator: wave 0, segmented suffix-sum -> 1 atomic per segment
        if (wv == 0) {
            int sgl = sSeg[cur][lane];
            float v = sEx[cur][lane];
#pragma unroll
            for (int off = 1; off < 64; off <<= 1) {
                float o = __shfl_down(v, off);
                int  so = __shfl_down(sgl, off);
                if (lane + off < 64 && so == sgl) v += o;
            }
            bool head = (lane == 0) || (sSeg[cur][lane - 1] != sgl);
            if (head && v != 0.f) atomicAdd(&denom[sgl], v);
        }
        // weighted row sum: grp g scans nodes g*32..g*32+31, thread owns dim sd
        {
            float a = 0.f;
            int j0 = grp * 32;
            int curS = sSeg[cur][j0];
#pragma unroll 4
            for (int j = j0; j < j0 + 32; ++j) {
                int s2 = sSeg[cur][j];
                if (s2 != curS) {
                    atomicAdd(&rstu[((size_t)curS << 7) + sd], a);
                    a = 0.f; curS = s2;
                }
                int addr = j * 128 + sbase + ((c7 ^ (j & 7)) << 3);
                a += sEx[cur][j] * bf2f(sA[cur][addr]);
            }
            atomicAdd(&rstu[((size_t)curS << 7) + sd], a);
        }
        if (!hn) break;
        T = Tn; cur ^= 1;
    }
}

// ---------------- K6: out = (scale*rstu/denom + shift*(denom>0)) @ W_out ----------------
__global__ __launch_bounds__(256) void k_out(const float* __restrict__ rstu, const float* __restrict__ denomA,
                                             const float* __restrict__ dsum, const float* __restrict__ dsumsq,
                                             const float* __restrict__ gamma, const float* __restrict__ beta,
                                             const float* __restrict__ Wout, float* __restrict__ out,
                                             float invN, int B) {
    __shared__ float sT[128][36];
    __shared__ float sScale[128], sShift[128];
    int t = threadIdx.x;
    if (t < 128) {
        float mean = dsum[t] * invN;
        float var  = dsumsq[t] * invN - mean * mean;
        float sc   = gamma[t] * rsqrtf(var + 1e-5f);
        sScale[t] = sc;
        sShift[t] = beta[t] - mean * sc;
    }
    __syncthreads();
    int b0 = blockIdx.x * 32;
    for (int i = 0; i < 16; ++i) {
        int idx = i * 256 + t;
        int r = idx >> 7, d = idx & 127;
        int b = min(b0 + r, B - 1);
        float dn = denomA[b];
        float inv = (dn > 0.f) ? 1.f / dn : 0.f;
        float msk = (dn > 0.f) ? 1.f : 0.f;
        sT[d][r] = rstu[((size_t)b << 7) + d] * sScale[d] * inv + sShift[d] * msk;
    }
    __syncthreads();
    float acc[32];
#pragma unroll
    for (int r = 0; r < 32; ++r) acc[r] = 0.f;
    for (int dd = 0; dd < 128; ++dd) {
        float w = Wout[dd * 256 + t];
        const float4* row = (const float4*)&sT[dd][0];
#pragma unroll
        for (int r4 = 0; r4 < 8; ++r4) {
            float4 v = row[r4];
            acc[r4 * 4 + 0] += w * v.x;
            acc[r4 * 4 + 1] += w * v.y;
            acc[r4 * 4 + 2] += w * v.z;
            acc[r4 * 4 + 3] += w * v.w;
        }
    }
    for (int r = 0; r < 32; ++r)
        if (b0 + r < B) out[(size_t)(b0 + r) * 256 + t] = acc[r];
}

extern "C" void kernel_launch(void* const* d_in, const int* in_sizes, int n_in,
                              void* d_out, int out_size, void* d_ws, size_t ws_size,
                              hipStream_t stream) {
    const float* feat  = (const float*)d_in[0];
    const int*   iid   = (const int*)d_in[1];
    const int*   seg   = (const int*)d_in[2];
    const int*   last  = (const int*)d_in[3];
    const float* gamma = (const float*)d_in[4];
    const float* beta  = (const float*)d_in[5];
    const float* Wu    = (const float*)d_in[6];
    const float* Wv    = (const float*)d_in[7];
    const float* bv    = (const float*)d_in[8];
    const float* we    = (const float*)d_in[9];
    const float* Wout  = (const float*)d_in[10];
    float* out = (float*)d_out;

    int V = in_sizes[0] / 128;
    int N = in_sizes[1];
    int B = in_sizes[3];
    float invN = 1.0f / (float)N;

    char* w = (char*)d_ws;
    size_t off = 0;
    auto alloc = [&](size_t bytes) -> void* {
        void* p = w + off;
        off += (bytes + 255) & ~(size_t)255;
        return p;
    };
    // zero-init region
    int*   counts = (int*)alloc((size_t)V * 4);
    float* dsum   = (float*)alloc(512);
    float* dsumsq = (float*)alloc(512);
    float* denom  = (float*)alloc((size_t)B * 4);
    float* rstu   = (float*)alloc((size_t)B * 128 * 4);
    size_t zero_bytes = off;
    // rest
    unsigned short* wut = (unsigned short*)alloc(128 * 128 * 2);
    float* cvec   = (float*)alloc(512);
    float* fv     = (float*)alloc((size_t)B * 128 * 4);
    unsigned short* featb = (unsigned short*)alloc((size_t)V * 128 * 2);
    float* exo    = (float*)alloc((size_t)N * 4);
    (void)ws_size; (void)n_in; (void)out_size;

    hipMemsetAsync(d_ws, 0, zero_bytes, stream);

    k_hist<<<(N + 255) / 256, 256, 0, stream>>>(iid, counts, N);
    k_cvtstats<<<1024, 256, 0, stream>>>(feat, counts, featb, dsum, dsumsq, V);
    k_mid<<<1 + (B + 31) / 32, 256, 0, stream>>>(feat, iid, last, dsum, dsumsq, gamma, beta,
                                                 Wu, Wv, bv, wut, cvec, fv, invN, B);
    int numTiles = (N + 63) / 64;
    k_main<<<768, 256, 0, stream>>>(featb, iid, seg, wut, fv, we, cvec, exo, N, B, numTiles);
    k_sum<<<1024, 256, 0, stream>>>(featb, iid, seg, exo, denom, rstu, N, numTiles);
    k_out<<<(B + 31) / 32, 256, 0, stream>>>(rstu, denom, dsum, dsumsq, gamma, beta, Wout, out, invN, B);
}

// Round 7
// 452.314 us; speedup vs baseline: 1.3475x; 1.0334x over previous
//
#include <hip/hip_runtime.h>

typedef __attribute__((ext_vector_type(8))) short short8;
typedef __attribute__((ext_vector_type(4))) float floatx4;

static __device__ __forceinline__ unsigned short f2bf(float x) {
    unsigned int u = __float_as_uint(x);
    u += 0x7fffu + ((u >> 16) & 1u);
    return (unsigned short)(u >> 16);
}
static __device__ __forceinline__ float bf2f(unsigned short h) {
    return __uint_as_float(((unsigned int)h) << 16);
}

// ---------------- K1: histogram of iid ----------------
__global__ void k_hist(const int* __restrict__ iid, int* __restrict__ counts, int N) {
    int n = blockIdx.x * blockDim.x + threadIdx.x;
    if (n < N) atomicAdd(&counts[iid[n]], 1);
}

// ---------------- K2: fp32->bf16 convert + count-weighted stats ----------------
// 8 rows / block-iter, float4 per thread (4 dims), LDS-reduced then atomics.
__global__ __launch_bounds__(256) void k_cvtstats(const float* __restrict__ feat,
                                                  const int* __restrict__ counts,
                                                  unsigned short* __restrict__ featb,
                                                  float* __restrict__ dsum, float* __restrict__ dsumsq,
                                                  int V) {
    int tid = threadIdx.x;
    int r8 = tid >> 5, lane32 = tid & 31;
    int q4 = lane32 * 4;
    float s0 = 0.f, s1 = 0.f, s2 = 0.f, s3 = 0.f;
    float q0 = 0.f, q1 = 0.f, q2 = 0.f, q3 = 0.f;
    for (int v0 = blockIdx.x * 8; v0 < V; v0 += gridDim.x * 8) {
        int v = v0 + r8;
        if (v >= V) continue;
        float4 f = *(const float4*)&feat[(size_t)v * 128 + q4];
        ushort4 u;
        u.x = f2bf(f.x); u.y = f2bf(f.y); u.z = f2bf(f.z); u.w = f2bf(f.w);
        *(ushort4*)&featb[(size_t)v * 128 + q4] = u;
        float c = (float)counts[v];
        if (c != 0.f) {
            s0 += c * f.x; s1 += c * f.y; s2 += c * f.z; s3 += c * f.w;
            q0 += c * f.x * f.x; q1 += c * f.y * f.y;
            q2 += c * f.z * f.z; q3 += c * f.w * f.w;
        }
    }
    __shared__ float4 red4[256];
    red4[tid] = make_float4(s0, s1, s2, s3);
    __syncthreads();
    if (tid < 128) {
        int l32 = tid >> 2, j = tid & 3;
        float t = 0.f;
        for (int k = 0; k < 8; ++k) t += (&red4[k * 32 + l32].x)[j];
        atomicAdd(&dsum[tid], t);
    }
    __syncthreads();
    red4[tid] = make_float4(q0, q1, q2, q3);
    __syncthreads();
    if (tid < 128) {
        int l32 = tid >> 2, j = tid & 3;
        float t = 0.f;
        for (int k = 0; k < 8; ++k) t += (&red4[k * 32 + l32].x)[j];
        atomicAdd(&dsumsq[tid], t);
    }
}

// ---------------- K3: merged prep (block 0: wut+cvec) + fv (blocks 1..) --------------
__global__ __launch_bounds__(256) void k_mid(const float* __restrict__ feat, const int* __restrict__ iid,
                                             const int* __restrict__ last,
                                             const float* __restrict__ dsum, const float* __restrict__ dsumsq,
                                             const float* __restrict__ gamma, const float* __restrict__ beta,
                                             const float* __restrict__ Wu, const float* __restrict__ Wv,
                                             const float* __restrict__ bv,
                                             unsigned short* __restrict__ wut, float* __restrict__ cvec,
                                             float* __restrict__ fv, float invN, int B) {
    __shared__ float sScale[128], sShift[128];
    __shared__ float sx[32][128];
    int tid = threadIdx.x;
    if (tid < 128) {
        float mean = dsum[tid] * invN;
        float var  = dsumsq[tid] * invN - mean * mean;
        float sc   = gamma[tid] * rsqrtf(var + 1e-5f);
        sScale[tid] = sc;
        sShift[tid] = beta[tid] - mean * sc;
    }
    __syncthreads();
    if (blockIdx.x == 0) {
        for (int i = tid; i < 16384; i += 256) {
            int d2 = i >> 7, h = i & 127;
            wut[h * 128 + d2] = f2bf(sScale[d2] * Wu[i]);
        }
        if (tid < 128) {
            float a = 0.f;
            for (int d2 = 0; d2 < 128; ++d2) a += sShift[d2] * Wu[d2 * 128 + tid];
            cvec[tid] = a;
        }
        return;
    }
    int b0 = (blockIdx.x - 1) * 32;
    int h = tid & 127, half = tid >> 7;
    for (int g = half; g < 32; g += 2) {
        int b = b0 + g;
        int row = (b < B) ? iid[last[b]] : 0;
        sx[g][h] = feat[(size_t)row * 128 + h] * sScale[h] + sShift[h];
    }
    __syncthreads();
    float acc[16];
#pragma unroll
    for (int g = 0; g < 16; ++g) acc[g] = 0.f;
    for (int d2 = 0; d2 < 128; d2 += 4) {
        float w0 = Wv[(d2 + 0) * 128 + h];
        float w1 = Wv[(d2 + 1) * 128 + h];
        float w2 = Wv[(d2 + 2) * 128 + h];
        float w3 = Wv[(d2 + 3) * 128 + h];
#pragma unroll
        for (int g = 0; g < 16; ++g) {
            float4 xv = *(const float4*)&sx[half * 16 + g][d2];   // LDS broadcast
            acc[g] += xv.x * w0 + xv.y * w1 + xv.z * w2 + xv.w * w3;
        }
    }
    float cb = bv[h];
    for (int g = 0; g < 16; ++g) {
        int b = b0 + half * 16 + g;
        if (b < B) fv[(size_t)b * 128 + h] = acc[g] + cb;
    }
}

// ---------------- K4: pipelined e-kernel ----------------
// ex[n] = exp( w_e . sigmoid(bf16(feat[iid[n]]) @ Wu' + cvec + fv[seg[n]]) )
// loadRegs issued a FULL iteration ahead of its stage -> no exposed pre-barrier loads.
__global__ __launch_bounds__(256, 4) void k_main(
        const unsigned short* __restrict__ featb, const int* __restrict__ iid,
        const int* __restrict__ seg, const unsigned short* __restrict__ wut,
        const float* __restrict__ fv, const float* __restrict__ we_g,
        const float* __restrict__ cvec,
        float* __restrict__ exo, int N, int B, int numTiles) {
    __shared__ unsigned short sA[2][64 * 128];
    __shared__ int   sSeg[2][64];
    __shared__ float sFv[2][4][128];
    __shared__ float sEp[2][4][64];

    int tid = threadIdx.x;
    int wv = tid >> 6, lane = tid & 63, q = lane >> 4, c = lane & 15;
    int p2 = lane & 15;
    int rowbase = wv * 16 + (lane >> 4);

    short8 bfr[2][4];
    float we2[2], cv[2];
#pragma unroll
    for (int t = 0; t < 2; ++t) {
        int h = (2 * wv + t) * 16 + c;
        we2[t] = we_g[h];
        cv[t]  = cvec[h];
#pragma unroll
        for (int kc = 0; kc < 4; ++kc)
            bfr[t][kc] = *(const short8*)(wut + h * 128 + kc * 32 + q * 8);
    }

    if (blockIdx.x >= numTiles) return;

    int iidR[4]; int segR; float2 fvR;
    auto loadRegs = [&](int T) {
        int n0 = T << 6;
#pragma unroll
        for (int k = 0; k < 4; ++k)
            iidR[k] = iid[min(n0 + rowbase + 4 * k, N - 1)];
        segR = seg[min(n0 + (tid & 63), N - 1)];
        int s0 = seg[min(n0, N - 1)];
        int fvrow = min(s0 + (tid >> 6), B - 1);
        fvR = *(const float2*)(fv + (size_t)fvrow * 128 + ((tid << 1) & 127));
    };
    auto stage = [&](int buf) {
        unsigned short* sAb = &sA[buf][0];
#pragma unroll
        for (int k = 0; k < 4; ++k) {
            int row = rowbase + 4 * k;
            int j = (p2 & 8) | ((p2 & 7) ^ (row & 7));
            const unsigned short* g = featb + (size_t)iidR[k] * 128 + j * 8;
            __builtin_amdgcn_global_load_lds(
                (const __attribute__((address_space(1))) void*)g,
                (__attribute__((address_space(3))) void*)(sAb + wv * 2048 + k * 512),
                16, 0, 0);
        }
        if (tid < 64) sSeg[buf][tid] = segR;
        *(float2*)&sFv[buf][tid >> 6][(tid << 1) & 127] = fvR;
    };

    int G = gridDim.x;
    int T = blockIdx.x;
    loadRegs(T);
    stage(0);
    loadRegs(T + G);            // prefetch for next stage (indices clamp-safe)
    int prevN0 = -1;
    int cur = 0;

    for (;;) {
        int Tn = T + G;
        bool hn = (Tn < numTiles);
        __syncthreads();            // buf[cur] DMA done (issued 1 iter ago); readers done
        if (hn) stage(cur ^ 1);     // uses regs loaded LAST iteration
        if (T + 2 * G < numTiles) loadRegs(T + 2 * G);   // in flight through this compute

        floatx4 acc[4][2];
#pragma unroll
        for (int mt = 0; mt < 4; ++mt)
#pragma unroll
            for (int t = 0; t < 2; ++t) acc[mt][t] = (floatx4)(0.f);
#pragma unroll
        for (int kc = 0; kc < 4; ++kc) {
            int jj = 4 * kc + q;
            int pofs = ((jj & 8) | ((jj & 7) ^ (c & 7))) * 8;
            short8 a0 = *(const short8*)&sA[cur][( 0 + c) * 128 + pofs];
            short8 a1 = *(const short8*)&sA[cur][(16 + c) * 128 + pofs];
            short8 a2 = *(const short8*)&sA[cur][(32 + c) * 128 + pofs];
            short8 a3 = *(const short8*)&sA[cur][(48 + c) * 128 + pofs];
#pragma unroll
            for (int t = 0; t < 2; ++t) {
                acc[0][t] = __builtin_amdgcn_mfma_f32_16x16x32_bf16(a0, bfr[t][kc], acc[0][t], 0, 0, 0);
                acc[1][t] = __builtin_amdgcn_mfma_f32_16x16x32_bf16(a1, bfr[t][kc], acc[1][t], 0, 0, 0);
                acc[2][t] = __builtin_amdgcn_mfma_f32_16x16x32_bf16(a2, bfr[t][kc], acc[2][t], 0, 0, 0);
                acc[3][t] = __builtin_amdgcn_mfma_f32_16x16x32_bf16(a3, bfr[t][kc], acc[3][t], 0, 0, 0);
            }
        }
        {
            int s0 = sSeg[cur][0];
            int h0 = wv * 32 + c;
#pragma unroll
            for (int mt = 0; mt < 4; ++mt)
#pragma unroll
                for (int r = 0; r < 4; ++r) {
                    int nl = mt * 16 + q * 4 + r;
                    int sg = sSeg[cur][nl];
                    int off = sg - s0;
                    float f0, f1;
                    if (off < 4) {
                        f0 = sFv[cur][off][h0];
                        f1 = sFv[cur][off][h0 + 16];
                    } else {
                        f0 = fv[((size_t)sg << 7) + h0];
                        f1 = fv[((size_t)sg << 7) + h0 + 16];
                    }
                    float u0 = acc[mt][0][r] + f0 + cv[0];
                    float u1 = acc[mt][1][r] + f1 + cv[1];
                    float p = we2[0] * __builtin_amdgcn_rcpf(1.f + __expf(-u0))
                            + we2[1] * __builtin_amdgcn_rcpf(1.f + __expf(-u1));
                    p += __shfl_xor(p, 1);
                    p += __shfl_xor(p, 2);
                    p += __shfl_xor(p, 4);
                    p += __shfl_xor(p, 8);
                    if (c == 0) sEp[cur][wv][nl] = p;
                }
        }
        if (prevN0 >= 0 && tid < 64) {
            int n = prevN0 + tid;
            if (n < N) {
                float s = sEp[cur ^ 1][0][tid] + sEp[cur ^ 1][1][tid]
                        + sEp[cur ^ 1][2][tid] + sEp[cur ^ 1][3][tid];
                exo[n] = __expf(s);
            }
        }
        prevN0 = T << 6;
        if (!hn) break;
        T = Tn; cur ^= 1;
    }
    __syncthreads();
    if (tid < 64) {
        int n = prevN0 + tid;
        if (n < N) {
            float s = sEp[cur][0][tid] + sEp[cur][1][tid]
                    + sEp[cur][2][tid] + sEp[cur][3][tid];
            exo[n] = __expf(s);
        }
    }
}

// ---------------- K5: weighted segment-sum, sequential tiles, DMA-staged ----------------
// 4 groups x 16 nodes; lane owns 2 dims (u32 LDS reads). denom: 1 atomic/segment.
__global__ __launch_bounds__(256, 4) void k_sum(
        const unsigned short* __restrict__ featb, const int* __restrict__ iid,
        const int* __restrict__ seg, const float* __restrict__ exo,
        float* __restrict__ denom, float* __restrict__ rstu,
        int N, int numTiles) {
    __shared__ unsigned short sA[2][64 * 128];
    __shared__ int   sSeg[2][64];
    __shared__ float sEx[2][64];

    int tid = threadIdx.x;
    int wv = tid >> 6, lane = tid & 63;
    int p2 = lane & 15;
    int rowbase = wv * 16 + (lane >> 4);

    if (blockIdx.x >= numTiles) return;

    int iidR[4]; int segR; float exR;
    auto loadRegs = [&](int T) {
        int n0 = T << 6;
#pragma unroll
        for (int k = 0; k < 4; ++k)
            iidR[k] = iid[min(n0 + rowbase + 4 * k, N - 1)];
        int n = n0 + lane;
        segR = seg[min(n, N - 1)];
        exR = (wv == 0 && n < N) ? exo[n] : 0.f;
    };
    auto stage = [&](int buf) {
        unsigned short* sAb = &sA[buf][0];
#pragma unroll
        for (int k = 0; k < 4; ++k) {
            int row = rowbase + 4 * k;
            int j = (p2 & 8) | ((p2 & 7) ^ (row & 7));
            const unsigned short* g = featb + (size_t)iidR[k] * 128 + j * 8;
            __builtin_amdgcn_global_load_lds(
                (const __attribute__((address_space(1))) void*)g,
                (__attribute__((address_space(3))) void*)(sAb + wv * 2048 + k * 512),
                16, 0, 0);
        }
        if (tid < 64) { sSeg[buf][tid] = segR; sEx[buf][tid] = exR; }
    };

    // scan layout: group g scans nodes g*16..+15; lane owns dims d0, d0+1
    int d0 = lane * 2;
    int cch = d0 >> 3, w = d0 & 7;
    int hi8 = cch & 8, c7 = cch & 7;

    int G = gridDim.x;
    int T = blockIdx.x;
    loadRegs(T);
    stage(0);
    loadRegs(T + G);
    int cur = 0;

    for (;;) {
        int Tn = T + G;
        bool hn = (Tn < numTiles);
        __syncthreads();
        if (hn) stage(cur ^ 1);
        if (T + 2 * G < numTiles) loadRegs(T + 2 * G);

        // denominator: wave 0, segmented suffix-sum -> 1 atomic per segment
        if (wv == 0) {
            int sgl = sSeg[cur][lane];
            float v = sEx[cur][lane];
#pragma unroll
            for (int off2 = 1; off2 < 64; off2 <<= 1) {
                float o = __shfl_down(v, off2);
                int  so = __shfl_down(sgl, off2);
                if (lane + off2 < 64 && so == sgl) v += o;
            }
            bool head = (lane == 0) || (sSeg[cur][lane - 1] != sgl);
            if (head && v != 0.f) atomicAdd(&denom[sgl], v);
        }
        // weighted row sum
        {
            float a0 = 0.f, a1 = 0.f;
            int j0 = wv * 16;
            int curS = sSeg[cur][j0];
#pragma unroll 4
            for (int j = j0; j < j0 + 16; ++j) {
                int s2 = sSeg[cur][j];
                if (s2 != curS) {
                    atomicAdd(&rstu[((size_t)curS << 7) + d0], a0);
                    atomicAdd(&rstu[((size_t)curS << 7) + d0 + 1], a1);
                    a0 = 0.f; a1 = 0.f; curS = s2;
                }
                int jx = hi8 | (c7 ^ (j & 7));
                unsigned u = *(const unsigned*)&sA[cur][j * 128 + jx * 8 + w];
                float e = sEx[cur][j];
                a0 += e * __uint_as_float(u << 16);
                a1 += e * __uint_as_float(u & 0xffff0000u);
            }
            atomicAdd(&rstu[((size_t)curS << 7) + d0], a0);
            atomicAdd(&rstu[((size_t)curS << 7) + d0 + 1], a1);
        }
        if (!hn) break;
        T = Tn; cur ^= 1;
    }
}

// ---------------- K6: out = (scale*rstu/denom + shift*(denom>0)) @ W_out ----------------
__global__ __launch_bounds__(256) void k_out(const float* __restrict__ rstu, const float* __restrict__ denomA,
                                             const float* __restrict__ dsum, const float* __restrict__ dsumsq,
                                             const float* __restrict__ gamma, const float* __restrict__ beta,
                                             const float* __restrict__ Wout, float* __restrict__ out,
                                             float invN, int B) {
    __shared__ float sT[128][36];
    __shared__ float sScale[128], sShift[128];
    int t = threadIdx.x;
    if (t < 128) {
        float mean = dsum[t] * invN;
        float var  = dsumsq[t] * invN - mean * mean;
        float sc   = gamma[t] * rsqrtf(var + 1e-5f);
        sScale[t] = sc;
        sShift[t] = beta[t] - mean * sc;
    }
    __syncthreads();
    int b0 = blockIdx.x * 32;
    for (int i = 0; i < 16; ++i) {
        int idx = i * 256 + t;
        int r = idx >> 7, d = idx & 127;
        int b = min(b0 + r, B - 1);
        float dn = denomA[b];
        float inv = (dn > 0.f) ? 1.f / dn : 0.f;
        float msk = (dn > 0.f) ? 1.f : 0.f;
        sT[d][r] = rstu[((size_t)b << 7) + d] * sScale[d] * inv + sShift[d] * msk;
    }
    __syncthreads();
    float acc[32];
#pragma unroll
    for (int r = 0; r < 32; ++r) acc[r] = 0.f;
    for (int dd = 0; dd < 128; ++dd) {
        float w = Wout[dd * 256 + t];
        const float4* row = (const float4*)&sT[dd][0];
#pragma unroll
        for (int r4 = 0; r4 < 8; ++r4) {
            float4 v = row[r4];
            acc[r4 * 4 + 0] += w * v.x;
            acc[r4 * 4 + 1] += w * v.y;
            acc[r4 * 4 + 2] += w * v.z;
            acc[r4 * 4 + 3] += w * v.w;
        }
    }
    for (int r = 0; r < 32; ++r)
        if (b0 + r < B) out[(size_t)(b0 + r) * 256 + t] = acc[r];
}

extern "C" void kernel_launch(void* const* d_in, const int* in_sizes, int n_in,
                              void* d_out, int out_size, void* d_ws, size_t ws_size,
                              hipStream_t stream) {
    const float* feat  = (const float*)d_in[0];
    const int*   iid   = (const int*)d_in[1];
    const int*   seg   = (const int*)d_in[2];
    const int*   last  = (const int*)d_in[3];
    const float* gamma = (const float*)d_in[4];
    const float* beta  = (const float*)d_in[5];
    const float* Wu    = (const float*)d_in[6];
    const float* Wv    = (const float*)d_in[7];
    const float* bv    = (const float*)d_in[8];
    const float* we    = (const float*)d_in[9];
    const float* Wout  = (const float*)d_in[10];
    float* out = (float*)d_out;

    int V = in_sizes[0] / 128;
    int N = in_sizes[1];
    int B = in_sizes[3];
    float invN = 1.0f / (float)N;

    char* w = (char*)d_ws;
    size_t off = 0;
    auto alloc = [&](size_t bytes) -> void* {
        void* p = w + off;
        off += (bytes + 255) & ~(size_t)255;
        return p;
    };
    // zero-init region
    int*   counts = (int*)alloc((size_t)V * 4);
    float* dsum   = (float*)alloc(512);
    float* dsumsq = (float*)alloc(512);
    float* denom  = (float*)alloc((size_t)B * 4);
    float* rstu   = (float*)alloc((size_t)B * 128 * 4);
    size_t zero_bytes = off;
    // rest
    unsigned short* wut = (unsigned short*)alloc(128 * 128 * 2);
    float* cvec   = (float*)alloc(512);
    float* fv     = (float*)alloc((size_t)B * 128 * 4);
    unsigned short* featb = (unsigned short*)alloc((size_t)V * 128 * 2);
    float* exo    = (float*)alloc((size_t)N * 4);
    (void)ws_size; (void)n_in; (void)out_size;

    hipMemsetAsync(d_ws, 0, zero_bytes, stream);

    k_hist<<<(N + 255) / 256, 256, 0, stream>>>(iid, counts, N);
    k_cvtstats<<<1024, 256, 0, stream>>>(feat, counts, featb, dsum, dsumsq, V);
    k_mid<<<1 + (B + 31) / 32, 256, 0, stream>>>(feat, iid, last, dsum, dsumsq, gamma, beta,
                                                 Wu, Wv, bv, wut, cvec, fv, invN, B);
    int numTiles = (N + 63) / 64;
    k_main<<<1024, 256, 0, stream>>>(featb, iid, seg, wut, fv, we, cvec, exo, N, B, numTiles);
    k_sum<<<1024, 256, 0, stream>>>(featb, iid, seg, exo, denom, rstu, N, numTiles);
    k_out<<<(B + 31) / 32, 256, 0, stream>>>(rstu, denom, dsum, dsumsq, gamma, beta, Wout, out, invN, B);
}

// Round 8
// 434.693 us; speedup vs baseline: 1.4021x; 1.0405x over previous
//
#include <hip/hip_runtime.h>

typedef __attribute__((ext_vector_type(8))) short short8;
typedef __attribute__((ext_vector_type(4))) float floatx4;

static __device__ __forceinline__ unsigned short f2bf(float x) {
    unsigned int u = __float_as_uint(x);
    u += 0x7fffu + ((u >> 16) & 1u);
    return (unsigned short)(u >> 16);
}

// ---------------- K1: histogram of iid ----------------
__global__ void k_hist(const int* __restrict__ iid, int* __restrict__ counts, int N) {
    int n = blockIdx.x * blockDim.x + threadIdx.x;
    if (n < N) atomicAdd(&counts[iid[n]], 1);
}

// ---------------- K2: fp32->bf16 convert + count-weighted stats ----------------
__global__ __launch_bounds__(256) void k_cvtstats(const float* __restrict__ feat,
                                                  const int* __restrict__ counts,
                                                  unsigned short* __restrict__ featb,
                                                  float* __restrict__ dsum, float* __restrict__ dsumsq,
                                                  int V) {
    int tid = threadIdx.x;
    int r8 = tid >> 5, lane32 = tid & 31;
    int q4 = lane32 * 4;
    float s0 = 0.f, s1 = 0.f, s2 = 0.f, s3 = 0.f;
    float q0 = 0.f, q1 = 0.f, q2 = 0.f, q3 = 0.f;
    for (int v0 = blockIdx.x * 8; v0 < V; v0 += gridDim.x * 8) {
        int v = v0 + r8;
        if (v >= V) continue;
        float4 f = *(const float4*)&feat[(size_t)v * 128 + q4];
        ushort4 u;
        u.x = f2bf(f.x); u.y = f2bf(f.y); u.z = f2bf(f.z); u.w = f2bf(f.w);
        *(ushort4*)&featb[(size_t)v * 128 + q4] = u;
        float c = (float)counts[v];
        if (c != 0.f) {
            s0 += c * f.x; s1 += c * f.y; s2 += c * f.z; s3 += c * f.w;
            q0 += c * f.x * f.x; q1 += c * f.y * f.y;
            q2 += c * f.z * f.z; q3 += c * f.w * f.w;
        }
    }
    __shared__ float4 red4[256];
    red4[tid] = make_float4(s0, s1, s2, s3);
    __syncthreads();
    if (tid < 128) {
        int l32 = tid >> 2, j = tid & 3;
        float t = 0.f;
        for (int k = 0; k < 8; ++k) t += (&red4[k * 32 + l32].x)[j];
        atomicAdd(&dsum[tid], t);
    }
    __syncthreads();
    red4[tid] = make_float4(q0, q1, q2, q3);
    __syncthreads();
    if (tid < 128) {
        int l32 = tid >> 2, j = tid & 3;
        float t = 0.f;
        for (int k = 0; k < 8; ++k) t += (&red4[k * 32 + l32].x)[j];
        atomicAdd(&dsumsq[tid], t);
    }
}

// ---------------- K3: merged prep (block 0: wut+cvec) + fv (blocks 1..) --------------
__global__ __launch_bounds__(256) void k_mid(const float* __restrict__ feat, const int* __restrict__ iid,
                                             const int* __restrict__ last,
                                             const float* __restrict__ dsum, const float* __restrict__ dsumsq,
                                             const float* __restrict__ gamma, const float* __restrict__ beta,
                                             const float* __restrict__ Wu, const float* __restrict__ Wv,
                                             const float* __restrict__ bv,
                                             unsigned short* __restrict__ wut, float* __restrict__ cvec,
                                             float* __restrict__ fv, float invN, int B) {
    __shared__ float sScale[128], sShift[128];
    __shared__ float sx[32][128];
    int tid = threadIdx.x;
    if (tid < 128) {
        float mean = dsum[tid] * invN;
        float var  = dsumsq[tid] * invN - mean * mean;
        float sc   = gamma[tid] * rsqrtf(var + 1e-5f);
        sScale[tid] = sc;
        sShift[tid] = beta[tid] - mean * sc;
    }
    __syncthreads();
    if (blockIdx.x == 0) {
        for (int i = tid; i < 16384; i += 256) {
            int d2 = i >> 7, h = i & 127;
            wut[h * 128 + d2] = f2bf(sScale[d2] * Wu[i]);
        }
        if (tid < 128) {
            float a = 0.f;
            for (int d2 = 0; d2 < 128; ++d2) a += sShift[d2] * Wu[d2 * 128 + tid];
            cvec[tid] = a;
        }
        return;
    }
    int b0 = (blockIdx.x - 1) * 32;
    int h = tid & 127, half = tid >> 7;
    for (int g = half; g < 32; g += 2) {
        int b = b0 + g;
        int row = (b < B) ? iid[last[b]] : 0;
        sx[g][h] = feat[(size_t)row * 128 + h] * sScale[h] + sShift[h];
    }
    __syncthreads();
    float acc[16];
#pragma unroll
    for (int g = 0; g < 16; ++g) acc[g] = 0.f;
    for (int d2 = 0; d2 < 128; d2 += 4) {
        float w0 = Wv[(d2 + 0) * 128 + h];
        float w1 = Wv[(d2 + 1) * 128 + h];
        float w2 = Wv[(d2 + 2) * 128 + h];
        float w3 = Wv[(d2 + 3) * 128 + h];
#pragma unroll
        for (int g = 0; g < 16; ++g) {
            float4 xv = *(const float4*)&sx[half * 16 + g][d2];
            acc[g] += xv.x * w0 + xv.y * w1 + xv.z * w2 + xv.w * w3;
        }
    }
    float cb = bv[h];
    for (int g = 0; g < 16; ++g) {
        int b = b0 + half * 16 + g;
        if (b < B) fv[(size_t)b * 128 + h] = acc[g] + cb;
    }
}

// ---------------- K4: fused e + weighted segment-sum, 1 barrier/tile ----------------
// iter i: B1 -> finish(T-1): ex from sealed sEp, chunk-local denom atomics,
//         per-wave 16-node scan -> rstu atomics (rows owned by wave)
//         -> stage(T+1) into the SAME rows (program order protects) -> MFMA(T) -> sEp
__global__ __launch_bounds__(256, 4) void k_main(
        const unsigned short* __restrict__ featb, const int* __restrict__ iid,
        const int* __restrict__ seg, const unsigned short* __restrict__ wut,
        const float* __restrict__ fv, const float* __restrict__ we_g,
        const float* __restrict__ cvec,
        float* __restrict__ denom, float* __restrict__ rstu,
        int N, int B, int numTiles) {
    __shared__ unsigned short sA[2][64 * 128];
    __shared__ int   sSeg[2][64];
    __shared__ float sFv[2][4][128];
    __shared__ float sEp[2][4][64];

    int tid = threadIdx.x;
    int wv = tid >> 6, lane = tid & 63, q = lane >> 4, c = lane & 15;
    int p2 = lane & 15;
    int rowbase = wv * 16 + (lane >> 4);

    short8 bfr[2][4];
    float we2[2], cv[2];
#pragma unroll
    for (int t = 0; t < 2; ++t) {
        int h = (2 * wv + t) * 16 + c;
        we2[t] = we_g[h];
        cv[t]  = cvec[h];
#pragma unroll
        for (int kc = 0; kc < 4; ++kc)
            bfr[t][kc] = *(const short8*)(wut + h * 128 + kc * 32 + q * 8);
    }

    if (blockIdx.x >= numTiles) return;

    int iidR[4]; int segR; float2 fvR;
    auto loadRegs = [&](int T) {
        int n0 = T << 6;
#pragma unroll
        for (int k = 0; k < 4; ++k)
            iidR[k] = iid[min(n0 + rowbase + 4 * k, N - 1)];
        segR = seg[min(n0 + wv * 16 + (lane & 15), N - 1)];   // wave's own 16 nodes
        int s0 = seg[min(n0, N - 1)];
        int fvrow = min(s0 + (tid >> 6), B - 1);
        fvR = *(const float2*)(fv + (size_t)fvrow * 128 + ((tid << 1) & 127));
    };
    auto stage = [&](int buf) {
        unsigned short* sAb = &sA[buf][0];
#pragma unroll
        for (int k = 0; k < 4; ++k) {
            int row = rowbase + 4 * k;
            int j = (p2 & 8) | ((p2 & 7) ^ (row & 7));
            const unsigned short* g = featb + (size_t)iidR[k] * 128 + j * 8;
            __builtin_amdgcn_global_load_lds(
                (const __attribute__((address_space(1))) void*)g,
                (__attribute__((address_space(3))) void*)(sAb + wv * 2048 + k * 512),
                16, 0, 0);
        }
        if (lane < 16) sSeg[buf][wv * 16 + lane] = segR;      // own-range write
        *(float2*)&sFv[buf][tid >> 6][(tid << 1) & 127] = fvR;
    };

    // scan constants: lane owns dims d0,d0+1; wave scans its own nodes [wv*16, wv*16+16)
    int d0 = lane * 2;
    int cch = d0 >> 3, wq = d0 & 7;
    int hi8 = cch & 8, c7 = cch & 7;

    // finish(Tp, pb): ex from sEp[pb], denom (chunk-local partial sums), scan sA[pb]
    auto finish = [&](int Tp, int pb) {
        float s = sEp[pb][0][lane] + sEp[pb][1][lane]
                + sEp[pb][2][lane] + sEp[pb][3][lane];
        int n = (Tp << 6) + lane;
        float exv = (n < N) ? __expf(s) : 0.f;
        int j0 = wv * 16;
        bool inR = ((lane >> 4) == wv);       // lanes whose index is in the wave's node range
        int sgl = inR ? sSeg[pb][lane] : 0x7fffffff;
        {
            float v = inR ? exv : 0.f;
            int lim = j0 + 16;
#pragma unroll
            for (int off2 = 1; off2 < 16; off2 <<= 1) {
                float o = __shfl_down(v, off2);
                int  so = __shfl_down(sgl, off2);
                if (inR && lane + off2 < lim && so == sgl) v += o;
            }
            bool head = inR && (lane == j0 || sSeg[pb][lane - 1] != sgl);
            if (head && v != 0.f) atomicAdd(&denom[sgl], v);   // partial per chunk: sums correctly
        }
        {
            float a0 = 0.f, a1 = 0.f;
            int curS = sSeg[pb][j0];
#pragma unroll 4
            for (int j = j0; j < j0 + 16; ++j) {
                int s2 = sSeg[pb][j];
                float e = __shfl(exv, j);
                if (s2 != curS) {
                    atomicAdd(&rstu[((size_t)curS << 7) + d0], a0);
                    atomicAdd(&rstu[((size_t)curS << 7) + d0 + 1], a1);
                    a0 = 0.f; a1 = 0.f; curS = s2;
                }
                int jx = hi8 | (c7 ^ (j & 7));
                unsigned u = *(const unsigned*)&sA[pb][j * 128 + jx * 8 + wq];
                a0 += e * __uint_as_float(u << 16);
                a1 += e * __uint_as_float(u & 0xffff0000u);
            }
            atomicAdd(&rstu[((size_t)curS << 7) + d0], a0);
            atomicAdd(&rstu[((size_t)curS << 7) + d0 + 1], a1);
        }
    };

    int G = gridDim.x;
    int T = blockIdx.x;
    loadRegs(T);
    stage(0);
    loadRegs(T + G);
    int prevT = -1;
    int cur = 0;

    for (;;) {
        __syncthreads();            // B1: stage(T) drained; sEp/sA/sSeg of T-1 sealed
        if (prevT >= 0) finish(prevT, cur ^ 1);
        bool hn = (T + G < numTiles);
        if (hn) stage(cur ^ 1);     // after this wave's scan of the same rows
        if (T + 2 * G < numTiles) loadRegs(T + 2 * G);

        floatx4 acc[4][2];
#pragma unroll
        for (int mt = 0; mt < 4; ++mt)
#pragma unroll
            for (int t = 0; t < 2; ++t) acc[mt][t] = (floatx4)(0.f);
#pragma unroll
        for (int kc = 0; kc < 4; ++kc) {
            int jj = 4 * kc + q;
            int pofs = ((jj & 8) | ((jj & 7) ^ (c & 7))) * 8;
            short8 a0 = *(const short8*)&sA[cur][( 0 + c) * 128 + pofs];
            short8 a1 = *(const short8*)&sA[cur][(16 + c) * 128 + pofs];
            short8 a2 = *(const short8*)&sA[cur][(32 + c) * 128 + pofs];
            short8 a3 = *(const short8*)&sA[cur][(48 + c) * 128 + pofs];
#pragma unroll
            for (int t = 0; t < 2; ++t) {
                acc[0][t] = __builtin_amdgcn_mfma_f32_16x16x32_bf16(a0, bfr[t][kc], acc[0][t], 0, 0, 0);
                acc[1][t] = __builtin_amdgcn_mfma_f32_16x16x32_bf16(a1, bfr[t][kc], acc[1][t], 0, 0, 0);
                acc[2][t] = __builtin_amdgcn_mfma_f32_16x16x32_bf16(a2, bfr[t][kc], acc[2][t], 0, 0, 0);
                acc[3][t] = __builtin_amdgcn_mfma_f32_16x16x32_bf16(a3, bfr[t][kc], acc[3][t], 0, 0, 0);
            }
        }
        {
            int s0 = sSeg[cur][0];
            int h0 = wv * 32 + c;
#pragma unroll
            for (int mt = 0; mt < 4; ++mt)
#pragma unroll
                for (int r = 0; r < 4; ++r) {
                    int nl = mt * 16 + q * 4 + r;
                    int sg = sSeg[cur][nl];
                    int off = sg - s0;
                    float f0, f1;
                    if (off < 4) {
                        f0 = sFv[cur][off][h0];
                        f1 = sFv[cur][off][h0 + 16];
                    } else {
                        f0 = fv[((size_t)sg << 7) + h0];
                        f1 = fv[((size_t)sg << 7) + h0 + 16];
                    }
                    float u0 = acc[mt][0][r] + f0 + cv[0];
                    float u1 = acc[mt][1][r] + f1 + cv[1];
                    float p = we2[0] * __builtin_amdgcn_rcpf(1.f + __expf(-u0))
                            + we2[1] * __builtin_amdgcn_rcpf(1.f + __expf(-u1));
                    p += __shfl_xor(p, 1);
                    p += __shfl_xor(p, 2);
                    p += __shfl_xor(p, 4);
                    p += __shfl_xor(p, 8);
                    if (c == 0) sEp[cur][wv][nl] = p;
                }
        }
        prevT = T;
        if (!hn) break;
        T += G; cur ^= 1;
    }
    __syncthreads();                // seal sEp[cur] (+ last sA/sSeg already sealed)
    finish(prevT, cur);
}

// ---------------- K5: out = (scale*rstu/denom + shift*(denom>0)) @ W_out ----------------
__global__ __launch_bounds__(256) void k_out(const float* __restrict__ rstu, const float* __restrict__ denomA,
                                             const float* __restrict__ dsum, const float* __restrict__ dsumsq,
                                             const float* __restrict__ gamma, const float* __restrict__ beta,
                                             const float* __restrict__ Wout, float* __restrict__ out,
                                             float invN, int B) {
    __shared__ float sT[128][36];
    __shared__ float sScale[128], sShift[128];
    int t = threadIdx.x;
    if (t < 128) {
        float mean = dsum[t] * invN;
        float var  = dsumsq[t] * invN - mean * mean;
        float sc   = gamma[t] * rsqrtf(var + 1e-5f);
        sScale[t] = sc;
        sShift[t] = beta[t] - mean * sc;
    }
    __syncthreads();
    int b0 = blockIdx.x * 32;
    for (int i = 0; i < 16; ++i) {
        int idx = i * 256 + t;
        int r = idx >> 7, d = idx & 127;
        int b = min(b0 + r, B - 1);
        float dn = denomA[b];
        float inv = (dn > 0.f) ? 1.f / dn : 0.f;
        float msk = (dn > 0.f) ? 1.f : 0.f;
        sT[d][r] = rstu[((size_t)b << 7) + d] * sScale[d] * inv + sShift[d] * msk;
    }
    __syncthreads();
    float acc[32];
#pragma unroll
    for (int r = 0; r < 32; ++r) acc[r] = 0.f;
    for (int dd = 0; dd < 128; ++dd) {
        float w = Wout[dd * 256 + t];
        const float4* row = (const float4*)&sT[dd][0];
#pragma unroll
        for (int r4 = 0; r4 < 8; ++r4) {
            float4 v = row[r4];
            acc[r4 * 4 + 0] += w * v.x;
            acc[r4 * 4 + 1] += w * v.y;
            acc[r4 * 4 + 2] += w * v.z;
            acc[r4 * 4 + 3] += w * v.w;
        }
    }
    for (int r = 0; r < 32; ++r)
        if (b0 + r < B) out[(size_t)(b0 + r) * 256 + t] = acc[r];
}

extern "C" void kernel_launch(void* const* d_in, const int* in_sizes, int n_in,
                              void* d_out, int out_size, void* d_ws, size_t ws_size,
                              hipStream_t stream) {
    const float* feat  = (const float*)d_in[0];
    const int*   iid   = (const int*)d_in[1];
    const int*   seg   = (const int*)d_in[2];
    const int*   last  = (const int*)d_in[3];
    const float* gamma = (const float*)d_in[4];
    const float* beta  = (const float*)d_in[5];
    const float* Wu    = (const float*)d_in[6];
    const float* Wv    = (const float*)d_in[7];
    const float* bv    = (const float*)d_in[8];
    const float* we    = (const float*)d_in[9];
    const float* Wout  = (const float*)d_in[10];
    float* out = (float*)d_out;

    int V = in_sizes[0] / 128;
    int N = in_sizes[1];
    int B = in_sizes[3];
    float invN = 1.0f / (float)N;

    char* w = (char*)d_ws;
    size_t off = 0;
    auto alloc = [&](size_t bytes) -> void* {
        void* p = w + off;
        off += (bytes + 255) & ~(size_t)255;
        return p;
    };
    // zero-init region
    int*   counts = (int*)alloc((size_t)V * 4);
    float* dsum   = (float*)alloc(512);
    float* dsumsq = (float*)alloc(512);
    float* denom  = (float*)alloc((size_t)B * 4);
    float* rstu   = (float*)alloc((size_t)B * 128 * 4);
    size_t zero_bytes = off;
    // rest
    unsigned short* wut = (unsigned short*)alloc(128 * 128 * 2);
    float* cvec   = (float*)alloc(512);
    float* fv     = (float*)alloc((size_t)B * 128 * 4);
    unsigned short* featb = (unsigned short*)alloc((size_t)V * 128 * 2);
    (void)ws_size; (void)n_in; (void)out_size;

    hipMemsetAsync(d_ws, 0, zero_bytes, stream);

    k_hist<<<(N + 255) / 256, 256, 0, stream>>>(iid, counts, N);
    k_cvtstats<<<1024, 256, 0, stream>>>(feat, counts, featb, dsum, dsumsq, V);
    k_mid<<<1 + (B + 31) / 32, 256, 0, stream>>>(feat, iid, last, dsum, dsumsq, gamma, beta,
                                                 Wu, Wv, bv, wut, cvec, fv, invN, B);
    int numTiles = (N + 63) / 64;
    k_main<<<1024, 256, 0, stream>>>(featb, iid, seg, wut, fv, we, cvec, denom, rstu, N, B, numTiles);
    k_out<<<(B + 31) / 32, 256, 0, stream>>>(rstu, denom, dsum, dsumsq, gamma, beta, Wout, out, invN, B);
}